// Round 5
// baseline (321.296 us; speedup 1.0000x reference)
//
#include <hip/hip_runtime.h>

// out[b,f] = x0[b,f] * dot(x[b,:], w) + bias[f] + x[b,f]
// B = 16384 rows, F = 2048 cols, fp32 throughout.
//
// Round 5: two-pass split. Rounds 0-4 established:
//   - HBM traffic volume is at its floor (268 MB/iter; harness poison
//     memsets thrash L3, exactly one input array stays resident).
//   - The monolithic load->reduce->store wave structure caps at
//     3.4-4.1 TB/s effective regardless of occupancy/pipelining/hints.
// Known-good references on this chip: copy 6.3 TB/s, RMSNorm-shaped
// row-reduce 4.9 TB/s. So split into two pure-stream passes:
//   k1: dots[b] = dot(x[b,:], w)      (read x only, write 64 KB to ws)
//   k2: out = x0*dots[row] + bias + x (pure elementwise, copy-shaped;
//       x re-read should hit L3 -- k1 just touched all 134 MB of it)
// Same stream => ordering is implicit. No LDS, no barriers anywhere.

#define F_DIM 2048
#define F4_ROW 512   // float4 per row
#define SLOTS 8      // f4 slots per lane per row: 512/64

typedef float f4 __attribute__((ext_vector_type(4)));

// ---- Pass 1: row dot-products (wave-per-row, grid-stride, 1-deep pipe) ----
__global__ __launch_bounds__(256) void dot_kernel(
    const float* __restrict__ x,
    const float* __restrict__ w,
    float* __restrict__ dots,
    int B)
{
    const int wave = threadIdx.x >> 6;
    const int lane = threadIdx.x & 63;
    const int wid  = blockIdx.x * 4 + wave;
    const int nw   = gridDim.x * 4;

    const f4* __restrict__ w4 = (const f4*)w;
    f4 wr[SLOTS];
    #pragma unroll
    for (int i = 0; i < SLOTS; ++i) wr[i] = w4[lane + 64 * i];

    f4 xa[SLOTS], xb[SLOTS];
    int row = wid;
    if (row < B) {
        const f4* __restrict__ xr = (const f4*)(x + (long long)row * F_DIM);
        #pragma unroll
        for (int i = 0; i < SLOTS; ++i) xa[i] = xr[lane + 64 * i];
    }
    for (; row < B; row += nw) {
        const int nrow = row + nw;
        if (nrow < B) {   // prefetch next row before the reduce
            const f4* __restrict__ xn = (const f4*)(x + (long long)nrow * F_DIM);
            #pragma unroll
            for (int i = 0; i < SLOTS; ++i) xb[i] = xn[lane + 64 * i];
        }
        float p = 0.0f;
        #pragma unroll
        for (int i = 0; i < SLOTS; ++i)
            p += xa[i][0] * wr[i][0] + xa[i][1] * wr[i][1]
               + xa[i][2] * wr[i][2] + xa[i][3] * wr[i][3];
        #pragma unroll
        for (int off = 32; off > 0; off >>= 1)
            p += __shfl_xor(p, off, 64);
        if (lane == 0) dots[row] = p;
        #pragma unroll
        for (int i = 0; i < SLOTS; ++i) xa[i] = xb[i];
    }
}

// ---- Pass 2: pure elementwise epilogue (copy-shaped streaming) ----
// Each thread handles 4 f4s per grid-stride step, lane-major (every VMEM
// instruction is a perfectly coalesced 1 KiB wave access).
__global__ __launch_bounds__(256) void epi_kernel(
    const float* __restrict__ x0,
    const float* __restrict__ x,
    const float* __restrict__ bias,
    const float* __restrict__ dots,
    float* __restrict__ out,
    long long total_f4)
{
    const f4* __restrict__ x04 = (const f4*)x0;
    const f4* __restrict__ x4  = (const f4*)x;
    const f4* __restrict__ bi4 = (const f4*)bias;
    f4*       __restrict__ o4  = (f4*)out;

    const long long stride = (long long)gridDim.x * 1024;  // 256 thr * 4 f4
    for (long long gb = (long long)blockIdx.x * 1024; gb < total_f4; gb += stride) {
        const long long g0 = gb + threadIdx.x;
        if (gb + 1024 <= total_f4) {
            // Fast path: full 4-batch, independent loads first (MLP).
            f4 a0 = x04[g0], a1 = x04[g0 + 256], a2 = x04[g0 + 512], a3 = x04[g0 + 768];
            f4 b0 = x4 [g0], b1 = x4 [g0 + 256], b2 = x4 [g0 + 512], b3 = x4 [g0 + 768];
            float d0 = dots[(g0)       >> 9];
            float d1 = dots[(g0 + 256) >> 9];
            float d2 = dots[(g0 + 512) >> 9];
            float d3 = dots[(g0 + 768) >> 9];
            f4 v0 = bi4[(g0)       & 511];
            f4 v1 = bi4[(g0 + 256) & 511];
            f4 v2 = bi4[(g0 + 512) & 511];
            f4 v3 = bi4[(g0 + 768) & 511];
            o4[g0]       = a0 * d0 + (v0 + b0);
            o4[g0 + 256] = a1 * d1 + (v1 + b1);
            o4[g0 + 512] = a2 * d2 + (v2 + b2);
            o4[g0 + 768] = a3 * d3 + (v3 + b3);
        } else {
            for (int k = 0; k < 4; ++k) {
                const long long g = g0 + k * 256;
                if (g < total_f4) {
                    f4 a = x04[g], b = x4[g];
                    o4[g] = a * dots[g >> 9] + (bi4[g & 511] + b);
                }
            }
        }
    }
}

extern "C" void kernel_launch(void* const* d_in, const int* in_sizes, int n_in,
                              void* d_out, int out_size, void* d_ws, size_t ws_size,
                              hipStream_t stream) {
    const float* x0   = (const float*)d_in[0];
    const float* x    = (const float*)d_in[1];
    const float* w    = (const float*)d_in[2];
    const float* bias = (const float*)d_in[3];
    float* out  = (float*)d_out;
    float* dots = (float*)d_ws;   // B floats = 64 KiB, fits any workspace

    const int B = in_sizes[0] / F_DIM;              // 16384 rows
    const long long total_f4 = (long long)B * F4_ROW;

    // k1: 1024 blocks = 4096 waves, 4 rows/wave (grid-stride).
    dot_kernel<<<1024, 256, 0, stream>>>(x, w, dots, B);
    // k2: 2048 blocks, 4 f4/thread/step, 4 steps.
    epi_kernel<<<2048, 256, 0, stream>>>(x0, x, bias, dots, out, total_f4);
}

// Round 6
// 307.426 us; speedup vs baseline: 1.0451x; 1.0451x over previous
//
#include <hip/hip_runtime.h>

// out[b,f] = x0[b,f] * dot(x[b,:], w) + bias[f] + x[b,f]
// B = 16384 rows, F = 2048 cols, fp32 throughout.
//
// Round 6: the missing cell of the load/store-policy factorial.
// Established so far (dispatch times):
//   cache-load + cache-store : 108-112  (r0/r1)
//   cache-load + nt-store    : 118      (r4)
//   nt-load    + nt-store    : 99       (r3, current best)
//   nt-load    + cache-store : THIS KERNEL -- additive model predicts ~89-93.
// Mechanism: nt on x0 avoids churning L3 with a stream that can never stay
// resident (FETCH pinned at one array in every round); but nt on the STORE
// bypasses memory-side write-combining in L3 -- the harness's own fill
// kernel proves caching writes sustain 6.87 TB/s. So: stream the read,
// buffer the write.
// Everything else is byte-identical to round 3's kernel: 4 rows/wave,
// w+bias in registers once per wave, 1-deep cross-row prefetch pipeline,
// zero LDS, zero barriers.

#define F_DIM 2048
#define SLOTS 8   // float4 slots per lane: (F_DIM/4)/64
#define ROWS  4   // rows processed per wave

typedef float f4 __attribute__((ext_vector_type(4)));

__global__ __launch_bounds__(256) void cross_row_kernel(
    const float* __restrict__ x0,
    const float* __restrict__ x,
    const float* __restrict__ w,
    const float* __restrict__ bias,
    float* __restrict__ out)
{
    const int wave = threadIdx.x >> 6;
    const int lane = threadIdx.x & 63;
    const long long wid  = (long long)blockIdx.x * 4 + wave;
    const long long row0 = wid * ROWS;

    const f4* __restrict__ w4  = (const f4*)w;
    const f4* __restrict__ bi4 = (const f4*)bias;

    // Per-wave invariants: full w and bias rows in registers.
    f4 wr[SLOTS], br[SLOTS];
    #pragma unroll
    for (int i = 0; i < SLOTS; ++i) wr[i] = w4 [lane + 64 * i];
    #pragma unroll
    for (int i = 0; i < SLOTS; ++i) br[i] = bi4[lane + 64 * i];

    const f4* __restrict__ xbase  = (const f4*)(x  + row0 * F_DIM);
    const f4* __restrict__ x0base = (const f4*)(x0 + row0 * F_DIM);
    f4*       __restrict__ obase  = (f4*)(out + row0 * F_DIM);
    const int F4 = F_DIM / 4;  // 512 f4 per row

    f4 xa[SLOTS], x0a[SLOTS];   // current row
    f4 xb[SLOTS], x0b[SLOTS];   // prefetched next row

    // Prologue: row 0 in flight. x loads caching (x is the L3-resident
    // array); x0 loads nontemporal (pure stream, don't churn L3).
    #pragma unroll
    for (int i = 0; i < SLOTS; ++i) xa[i] = xbase[lane + 64 * i];
    #pragma unroll
    for (int i = 0; i < SLOTS; ++i)
        x0a[i] = __builtin_nontemporal_load(&x0base[lane + 64 * i]);

    #pragma unroll
    for (int r = 0; r < ROWS; ++r) {
        // Prefetch row r+1 BEFORE the reduce, so the dot's vmcnt wait
        // always has the next row's 16 KiB streaming underneath it.
        if (r + 1 < ROWS) {
            const f4* __restrict__ xn  = xbase  + (r + 1) * F4;
            const f4* __restrict__ x0n = x0base + (r + 1) * F4;
            #pragma unroll
            for (int i = 0; i < SLOTS; ++i) xb[i] = xn[lane + 64 * i];
            #pragma unroll
            for (int i = 0; i < SLOTS; ++i)
                x0b[i] = __builtin_nontemporal_load(&x0n[lane + 64 * i]);
        }

        // Per-lane partial dot (32 elements), then 64-lane butterfly.
        float partial = 0.0f;
        #pragma unroll
        for (int i = 0; i < SLOTS; ++i)
            partial += xa[i][0] * wr[i][0] + xa[i][1] * wr[i][1]
                     + xa[i][2] * wr[i][2] + xa[i][3] * wr[i][3];
        #pragma unroll
        for (int off = 32; off > 0; off >>= 1)
            partial += __shfl_xor(partial, off, 64);
        const float dot = partial;

        // Epilogue: x0*dot + bias + x. CACHING store -- let the
        // memory-side L3 write-combine and schedule the HBM writeback
        // (the 6.87 TB/s fill kernel is the existence proof).
        f4* __restrict__ o = obase + r * F4;
        #pragma unroll
        for (int i = 0; i < SLOTS; ++i) {
            f4 ov;
            ov[0] = x0a[i][0] * dot + (br[i][0] + xa[i][0]);
            ov[1] = x0a[i][1] * dot + (br[i][1] + xa[i][1]);
            ov[2] = x0a[i][2] * dot + (br[i][2] + xa[i][2]);
            ov[3] = x0a[i][3] * dot + (br[i][3] + xa[i][3]);
            o[lane + 64 * i] = ov;
        }

        // Rotate pipeline registers (statically unrolled -> pure renaming).
        #pragma unroll
        for (int i = 0; i < SLOTS; ++i) { xa[i] = xb[i]; x0a[i] = x0b[i]; }
    }
}

extern "C" void kernel_launch(void* const* d_in, const int* in_sizes, int n_in,
                              void* d_out, int out_size, void* d_ws, size_t ws_size,
                              hipStream_t stream) {
    const float* x0   = (const float*)d_in[0];
    const float* x    = (const float*)d_in[1];
    const float* w    = (const float*)d_in[2];
    const float* bias = (const float*)d_in[3];
    float* out = (float*)d_out;

    const int B = in_sizes[0] / F_DIM;          // 16384 rows
    const int blocks = B / (4 * ROWS);          // 4 waves/block * ROWS rows/wave
    cross_row_kernel<<<blocks, 256, 0, stream>>>(x0, x, w, bias, out);
}